// Round 6
// baseline (30585.574 us; speedup 1.0000x reference)
//
#include <hip/hip_runtime.h>
#include <math.h>

static constexpr int NN = 100000;          // nodes
static constexpr int DD = 16;              // out-degree
static constexpr int FF = 128;             // features
static constexpr int EE = NN * DD;         // 1,600,000 edges
static constexpr int EN = EE + NN;         // edges + self loops
static constexpr int MWORDS = (NN + 31) / 32;   // 3125
static constexpr int CHUNK  = 128;              // nodes per staged chunk
static constexpr int NCHUNK = (NN + CHUNK - 1) / CHUNK;  // 782 (last = 32 nodes)

// ---- d_ws layout (bytes) ----
static constexpr size_t WS_CNT     = 0;
static constexpr size_t WS_DINV    = 400000;
static constexpr size_t WS_WGT     = 800000;
static constexpr size_t WS_CLUSTER = 7200000;
static constexpr size_t WS_PARTNER = 7600000;
static constexpr size_t WS_MAXV    = 8000000;

// ---- d_out layout (float32 elements) ----
static constexpr size_t OUT_X    = 0;                      // NN*FF
static constexpr size_t OUT_POS  = (size_t)NN * FF;        // NN*2
static constexpr size_t OUT_EI   = OUT_POS + (size_t)NN*2; // 2*EN
static constexpr size_t OUT_ATTR = OUT_EI + (size_t)2*EN;  // EN*2

__global__ void k_zero(int* __restrict__ cnt, unsigned int* __restrict__ maxv) {
    int i = blockIdx.x * blockDim.x + threadIdx.x;
    if (i < NN) cnt[i] = 0;
    if (i == 0) *maxv = 0u;
}

__global__ void k_deg(const int* __restrict__ col, int* __restrict__ cnt) {
    int e = blockIdx.x * blockDim.x + threadIdx.x;
    if (e < EE) atomicAdd(&cnt[col[e]], 1);
}

__global__ void k_dinv(const int* __restrict__ cnt, float* __restrict__ dinv) {
    int i = blockIdx.x * blockDim.x + threadIdx.x;
    if (i < NN) dinv[i] = __fdiv_rn(1.0f, __fadd_rn((float)cnt[i], 1e-8f));
}

// weight[e] = dist(pos[row],pos[col]) * (dinv[row]+dinv[col]); rn ops only (no FMA).
__global__ void k_weight(const int* __restrict__ col, const float* __restrict__ pos,
                         const float* __restrict__ dinv, float* __restrict__ wgt) {
    int e = blockIdx.x * blockDim.x + threadIdx.x;
    if (e >= EE) return;
    int r = e >> 4;
    int c = col[e];
    float dx = __fsub_rn(pos[2*r],   pos[2*c]);
    float dy = __fsub_rn(pos[2*r+1], pos[2*c+1]);
    float dist = __fsqrt_rn(__fadd_rn(__fmul_rn(dx, dx), __fmul_rn(dy, dy)));
    wgt[e] = __fmul_rn(dist, __fadd_rn(dinv[r], dinv[c]));
}

// 16-lane all-reduce max (row-confined; rows never mix).
template <int CTRL>
static __device__ __forceinline__ float maxr(float m) {
#if __has_builtin(__builtin_amdgcn_mov_dpp)
    int x = __builtin_amdgcn_mov_dpp(__float_as_int(m), CTRL, 0xF, 0xF, true);
    return fmaxf(m, __int_as_float(x));
#else
    return m;  // unused; fallback path below
#endif
}

static __device__ __forceinline__ float row16_max(float wm) {
#if __has_builtin(__builtin_amdgcn_mov_dpp)
    float m = wm;
    m = maxr<0x128>(m);  // row_ror:8
    m = maxr<0x124>(m);  // row_ror:4
    m = maxr<0x122>(m);  // row_ror:2
    m = maxr<0x121>(m);  // row_ror:1
    return m;
#else
    float m = wm;
    m = fmaxf(m, __shfl_xor(m, 8, 16));
    m = fmaxf(m, __shfl_xor(m, 4, 16));
    m = fmaxf(m, __shfl_xor(m, 2, 16));
    m = fmaxf(m, __shfl_xor(m, 1, 16));
    return m;
#endif
}

// matched-word address for the prefetch read: lanes 0-15 -> candidate word,
// lane 16 -> self word of `node`, others -> 0; clamp garbage.
static __device__ __forceinline__ unsigned raddr(int cnb, int node, int t) {
    unsigned w = ((unsigned)cnb) >> 5;
    if (t >= 16) w = (t == 16) ? (((unsigned)node) >> 5) : 0u;
    return (w < (unsigned)MWORDS) ? w : 0u;
}

// Exact graclus matching, wave-cooperative (1 block, 64 threads = 1 wave).
// Lanes 0-15 hold the 16 candidates of the current node; grabs recorded in a
// LDS bitset. Candidate validity uses the theorem nb > i (heads never marked).
// col/wgt double-buffer-staged to LDS per 128-node chunk; matched-words are
// prefetched depth-2 and patched against the last grab (j1; j2 = insurance).
__global__ void __launch_bounds__(64)
k_match(const int* __restrict__ col, const float* __restrict__ wgt,
        int* __restrict__ cluster, int* __restrict__ partner) {
    __shared__ unsigned int matched[MWORDS];
    __shared__ int   cbuf[2][CHUNK * 16 + 64];   // +64 pad: lane-strided tail reads
    __shared__ float wbuf[2][CHUNK * 16 + 64];

    const int t = threadIdx.x;
    for (int idx = t; idx < MWORDS; idx += 64) matched[idx] = 0u;

    int4   creg[8] = {};
    float4 wreg[8] = {};

    // stage chunk 0: global -> regs -> LDS buf0
#pragma unroll 8
    for (int u = 0; u < 8; ++u) {
        int g = u * 256 + t * 4;
        if (g < EE) {
            creg[u] = *(const int4*)(col + g);
            wreg[u] = *(const float4*)(wgt + g);
        }
    }
#pragma unroll 8
    for (int u = 0; u < 8; ++u) {
        int off = u * 256 + t * 4;
        *(int4*)&cbuf[0][off]   = creg[u];
        *(float4*)&wbuf[0][off] = wreg[u];
    }
    // issue loads for chunk 1 (written to LDS at c=0 body)
#pragma unroll 8
    for (int u = 0; u < 8; ++u) {
        int g = 2048 + u * 256 + t * 4;
        if (g < EE) {
            creg[u] = *(const int4*)(col + g);
            wreg[u] = *(const float4*)(wgt + g);
        }
    }
    __syncthreads();

    int j1 = -1, j2 = -1;

    for (int c = 0; c < NCHUNK; ++c) {
        const int b = c & 1;
        // write chunk c+1 (loaded last round) into the other buffer
        if (c + 1 < NCHUNK) {
            const int ob = (c + 1) & 1;
#pragma unroll 8
            for (int u = 0; u < 8; ++u) {
                int off = u * 256 + t * 4;
                *(int4*)&cbuf[ob][off]   = creg[u];
                *(float4*)&wbuf[ob][off] = wreg[u];
            }
        }
        // issue global loads for chunk c+2 (consumed next round)
        if (c + 2 < NCHUNK) {
            const int gb = (c + 2) * 2048;
#pragma unroll 8
            for (int u = 0; u < 8; ++u) {
                int g = gb + u * 256 + t * 4;
                if (g < EE) {
                    creg[u] = *(const int4*)(col + g);
                    wreg[u] = *(const float4*)(wgt + g);
                }
            }
        }

        const int base = c * CHUNK;
        const int cnt  = min(CHUNK, NN - base);

        // ---- pipeline prologue: col/wgt nodes 0,1,2; R(0), R(1) ----
        int   cA = cbuf[b][0 * 16 + t], cB = cbuf[b][1 * 16 + t], cC = cbuf[b][2 * 16 + t], cD = 0;
        float fA = wbuf[b][0 * 16 + t], fB = wbuf[b][1 * 16 + t], fC = wbuf[b][2 * 16 + t], fD = 0.0f;
        unsigned mA = matched[raddr(cA, base + 0, t)];
        unsigned mB = matched[raddr(cB, base + 1, t)];
        unsigned mC = 0u;

        for (int k = 0; k < cnt; ++k) {
            const int i = base + k;
            // depth-3 col/wgt read
            if (k + 3 < cnt) {
                cD = cbuf[b][(k + 3) * 16 + t];
                fD = wbuf[b][(k + 3) * 16 + t];
            }
            // ---- process node i with (cA, fA, mA) ----
            {
                const int nb = cA;
                bool ok = (t < 16) && (nb > i)
                          && (((mA >> (nb & 31)) & 1u) == 0u)
                          && (nb != j1) && (nb != j2);
                float wm = ok ? fA : -INFINITY;
                float m  = row16_max(wm);
                unsigned long long bal =
                    __ballot(wm == m) & 0xFFFFull;
                float maxw = __int_as_float(
                    __builtin_amdgcn_readlane(__float_as_int(m), 0));
                unsigned sw = (unsigned)__builtin_amdgcn_readlane((int)mA, 16);
                bool selfg = (((sw >> (i & 31)) & 1u) != 0u) || (i == j1) || (i == j2);
                bool has = (maxw > -INFINITY);
                int lanewin = (bal != 0ull) ? (int)__builtin_ctzll(bal) : 0;
                int j = __builtin_amdgcn_readlane(cA, lanewin);
                if (!selfg) {
                    if (t == 0) {
                        cluster[i] = i;
                        if (has) {
                            cluster[j] = i;
                            partner[i] = j;
                            atomicOr(&matched[((unsigned)j) >> 5], 1u << (j & 31));
                        } else {
                            partner[i] = -1;
                        }
                    }
                    j2 = j1; j1 = has ? j : -1;
                } else {
                    j2 = j1; j1 = -1;
                }
            }
            // depth-2 matched-word prefetch (after this node's ds_or)
            if (k + 2 < cnt) mC = matched[raddr(cC, base + k + 2, t)];
            // rotate pipeline registers
            cA = cB; cB = cC; cC = cD;
            fA = fB; fB = fC; fC = fD;
            mA = mB; mB = mC;
        }
        __syncthreads();
    }
}

// x_out[c][f] = head ? max(x[c][f], x[partner][f]) : 0
__global__ void k_pool_x(const float* __restrict__ x, const int* __restrict__ cluster,
                         const int* __restrict__ partner, float* __restrict__ x_out) {
    int idx = blockIdx.x * blockDim.x + threadIdx.x;
    if (idx >= NN * FF) return;
    int c = idx >> 7;
    float v = 0.0f;
    if (cluster[c] == c) {
        v = x[idx];
        int p = partner[c];
        if (p >= 0) v = fmaxf(v, x[p * FF + (idx & (FF - 1))]);
    }
    x_out[idx] = v;
}

__global__ void k_pool_pos(const float* __restrict__ pos, const int* __restrict__ cluster,
                           const int* __restrict__ partner, float* __restrict__ pos_out) {
    int c = blockIdx.x * blockDim.x + threadIdx.x;
    if (c >= NN) return;
    float px = 0.0f, py = 0.0f;
    if (cluster[c] == c) {
        px = pos[2*c]; py = pos[2*c+1];
        int p = partner[c];
        if (p >= 0) {  // (a+b)*0.5 == (a+b)/2 exactly
            px = __fmul_rn(__fadd_rn(px, pos[2*p]),   0.5f);
            py = __fmul_rn(__fadd_rn(py, pos[2*p+1]), 0.5f);
        }
    }
    pos_out[2*c] = px; pos_out[2*c+1] = py;
}

// pooled edge indices (as float) + global max |cart| over non-self edges
__global__ void k_edges_max(const int* __restrict__ col, const int* __restrict__ cluster,
                            const float* __restrict__ pos_out, float* __restrict__ out_ei,
                            unsigned int* __restrict__ maxv) {
    float m = 0.0f;
    for (int e = blockIdx.x * blockDim.x + threadIdx.x; e < EE;
         e += gridDim.x * blockDim.x) {
        int rc = cluster[e >> 4];
        int cc = cluster[col[e]];
        out_ei[e]      = (float)rc;
        out_ei[EN + e] = (float)cc;
        if (rc != cc) {
            float dx = __fsub_rn(pos_out[2*cc],   pos_out[2*rc]);
            float dy = __fsub_rn(pos_out[2*cc+1], pos_out[2*rc+1]);
            m = fmaxf(m, fmaxf(fabsf(dx), fabsf(dy)));
        }
    }
    for (int off = 32; off > 0; off >>= 1) m = fmaxf(m, __shfl_down(m, off));
    if ((threadIdx.x & 63) == 0) atomicMax(maxv, __float_as_uint(m));
}

__global__ void k_attr(const int* __restrict__ col, const int* __restrict__ cluster,
                       const float* __restrict__ pos_out,
                       const unsigned int* __restrict__ maxv,
                       float* __restrict__ out_ei, float* __restrict__ out_attr) {
    int e = blockIdx.x * blockDim.x + threadIdx.x;
    if (e >= EN) return;
    if (e < EE) {
        int rc = cluster[e >> 4];
        int cc = cluster[col[e]];
        float a0 = 1.0f, a1 = 1.0f;
        if (rc != cc) {
            float denom = __fmul_rn(2.0f, __uint_as_float(*maxv));
            float dx = __fsub_rn(pos_out[2*cc],   pos_out[2*rc]);
            float dy = __fsub_rn(pos_out[2*cc+1], pos_out[2*rc+1]);
            a0 = __fadd_rn(__fdiv_rn(dx, denom), 0.5f);
            a1 = __fadd_rn(__fdiv_rn(dy, denom), 0.5f);
        }
        out_attr[2*e] = a0; out_attr[2*e+1] = a1;
    } else {
        int i = e - EE;  // self loops appended after the EE pooled edges
        out_ei[e]      = (float)i;
        out_ei[EN + e] = (float)i;
        out_attr[2*e] = 1.0f; out_attr[2*e+1] = 1.0f;
    }
}

extern "C" void kernel_launch(void* const* d_in, const int* in_sizes, int n_in,
                              void* d_out, int out_size, void* d_ws, size_t ws_size,
                              hipStream_t stream) {
    const float* x   = (const float*)d_in[0];
    const float* pos = (const float*)d_in[1];
    const int*   ei  = (const int*)d_in[2];
    const int*   col = ei + EE;   // row = e>>4 by construction

    char* ws = (char*)d_ws;
    int*          cnt     = (int*)(ws + WS_CNT);
    float*        dinv    = (float*)(ws + WS_DINV);
    float*        wgt     = (float*)(ws + WS_WGT);
    int*          cluster = (int*)(ws + WS_CLUSTER);
    int*          partner = (int*)(ws + WS_PARTNER);
    unsigned int* maxv    = (unsigned int*)(ws + WS_MAXV);

    float* out   = (float*)d_out;
    float* out_x    = out + OUT_X;
    float* out_pos  = out + OUT_POS;
    float* out_ei   = out + OUT_EI;
    float* out_attr = out + OUT_ATTR;

    k_zero<<<(NN + 255) / 256, 256, 0, stream>>>(cnt, maxv);
    k_deg<<<(EE + 255) / 256, 256, 0, stream>>>(col, cnt);
    k_dinv<<<(NN + 255) / 256, 256, 0, stream>>>(cnt, dinv);
    k_weight<<<(EE + 255) / 256, 256, 0, stream>>>(col, pos, dinv, wgt);
    k_match<<<1, 64, 0, stream>>>(col, wgt, cluster, partner);
    k_pool_x<<<(NN * FF + 255) / 256, 256, 0, stream>>>(x, cluster, partner, out_x);
    k_pool_pos<<<(NN + 255) / 256, 256, 0, stream>>>(pos, cluster, partner, out_pos);
    k_edges_max<<<1024, 256, 0, stream>>>(col, cluster, out_pos, out_ei, maxv);
    k_attr<<<(EN + 255) / 256, 256, 0, stream>>>(col, cluster, out_pos, maxv,
                                                 out_ei, out_attr);
}

// Round 7
// 20135.135 us; speedup vs baseline: 1.5190x; 1.5190x over previous
//
#include <hip/hip_runtime.h>
#include <math.h>

static constexpr int NN = 100000;          // nodes
static constexpr int DD = 16;              // out-degree
static constexpr int FF = 128;             // features
static constexpr int EE = NN * DD;         // 1,600,000 edges
static constexpr int EN = EE + NN;         // edges + self loops
static constexpr int MWORDS = (NN + 31) / 32;   // 3125
static constexpr int CHUNK  = 128;              // nodes per staged chunk
static constexpr int NCHUNK = (NN + CHUNK - 1) / CHUNK;  // 782 (last = 32 nodes)

// ---- d_ws layout (bytes) ----
static constexpr size_t WS_CNT     = 0;
static constexpr size_t WS_DINV    = 400000;
static constexpr size_t WS_WGT     = 800000;
static constexpr size_t WS_CLUSTER = 7200000;
static constexpr size_t WS_PARTNER = 7600000;
static constexpr size_t WS_MAXV    = 8000000;

// ---- d_out layout (float32 elements) ----
static constexpr size_t OUT_X    = 0;                      // NN*FF
static constexpr size_t OUT_POS  = (size_t)NN * FF;        // NN*2
static constexpr size_t OUT_EI   = OUT_POS + (size_t)NN*2; // 2*EN
static constexpr size_t OUT_ATTR = OUT_EI + (size_t)2*EN;  // EN*2

__global__ void k_zero(int* __restrict__ cnt, unsigned int* __restrict__ maxv) {
    int i = blockIdx.x * blockDim.x + threadIdx.x;
    if (i < NN) cnt[i] = 0;
    if (i == 0) *maxv = 0u;
}

__global__ void k_deg(const int* __restrict__ col, int* __restrict__ cnt) {
    int e = blockIdx.x * blockDim.x + threadIdx.x;
    if (e < EE) atomicAdd(&cnt[col[e]], 1);
}

__global__ void k_dinv(const int* __restrict__ cnt, float* __restrict__ dinv) {
    int i = blockIdx.x * blockDim.x + threadIdx.x;
    if (i < NN) dinv[i] = __fdiv_rn(1.0f, __fadd_rn((float)cnt[i], 1e-8f));
}

// weight[e] = dist(pos[row],pos[col]) * (dinv[row]+dinv[col]); rn ops only (no FMA).
__global__ void k_weight(const int* __restrict__ col, const float* __restrict__ pos,
                         const float* __restrict__ dinv, float* __restrict__ wgt) {
    int e = blockIdx.x * blockDim.x + threadIdx.x;
    if (e >= EE) return;
    int r = e >> 4;
    int c = col[e];
    float dx = __fsub_rn(pos[2*r],   pos[2*c]);
    float dy = __fsub_rn(pos[2*r+1], pos[2*c+1]);
    float dist = __fsqrt_rn(__fadd_rn(__fmul_rn(dx, dx), __fmul_rn(dy, dy)));
    wgt[e] = __fmul_rn(dist, __fadd_rn(dinv[r], dinv[c]));
}

// 16-lane all-reduce max via DPP row_ror; row-confined, so all 4 rows of the
// wave reduce simultaneously.
template <int CTRL>
static __device__ __forceinline__ float maxr(float m) {
    int x = __builtin_amdgcn_mov_dpp(__float_as_int(m), CTRL, 0xF, 0xF, true);
    return fmaxf(m, __int_as_float(x));
}
static __device__ __forceinline__ float row16_max(float wm) {
    float m = wm;
    m = maxr<0x128>(m);  // row_ror:8
    m = maxr<0x124>(m);  // row_ror:4
    m = maxr<0x122>(m);  // row_ror:2
    m = maxr<0x121>(m);  // row_ror:1
    return m;
}

// Exact graclus matching, 4 nodes per wave-iteration (4 rows x 16 candidates).
// Grabs recorded in LDS bitset; validity theorem: candidate valid iff nb > node
// and nb not grabbed. Matched-word prefetch at group depth 2, patched against
// the in-flight group's grabs (jp0..3) in registers; intra-group grabs handled
// by wave-wide invalidation + re-reduce (exact first-max semantics preserved).
__global__ void __launch_bounds__(64)
k_match(const int* __restrict__ col, const float* __restrict__ wgt,
        int* __restrict__ cluster, int* __restrict__ partner) {
    __shared__ unsigned int matched[MWORDS];
    __shared__ int   cbuf[2][CHUNK * 16 + 64];
    __shared__ float wbuf[2][CHUNK * 16 + 64];

    const int t   = threadIdx.x;
    const int row = t >> 4;          // 0..3: which node of the group
    for (int idx = t; idx < MWORDS; idx += 64) matched[idx] = 0u;

    int4   creg[8] = {};
    float4 wreg[8] = {};

    // stage chunk 0: global -> regs -> LDS buf0
#pragma unroll 8
    for (int u = 0; u < 8; ++u) {
        int g = u * 256 + t * 4;
        if (g < EE) {
            creg[u] = *(const int4*)(col + g);
            wreg[u] = *(const float4*)(wgt + g);
        }
    }
#pragma unroll 8
    for (int u = 0; u < 8; ++u) {
        int off = u * 256 + t * 4;
        *(int4*)&cbuf[0][off]   = creg[u];
        *(float4*)&wbuf[0][off] = wreg[u];
    }
    // issue loads for chunk 1
#pragma unroll 8
    for (int u = 0; u < 8; ++u) {
        int g = 2048 + u * 256 + t * 4;
        if (g < EE) {
            creg[u] = *(const int4*)(col + g);
            wreg[u] = *(const float4*)(wgt + g);
        }
    }
    __syncthreads();

    int jp0 = -1, jp1 = -1, jp2 = -1, jp3 = -1;  // previous group's grabs

    for (int c = 0; c < NCHUNK; ++c) {
        const int b = c & 1;
        if (c + 1 < NCHUNK) {   // write chunk c+1 into the other buffer
            const int ob = (c + 1) & 1;
#pragma unroll 8
            for (int u = 0; u < 8; ++u) {
                int off = u * 256 + t * 4;
                *(int4*)&cbuf[ob][off]   = creg[u];
                *(float4*)&wbuf[ob][off] = wreg[u];
            }
        }
        if (c + 2 < NCHUNK) {   // issue global loads for chunk c+2
            const int gb = (c + 2) * 2048;
#pragma unroll 8
            for (int u = 0; u < 8; ++u) {
                int g = gb + u * 256 + t * 4;
                if (g < EE) {
                    creg[u] = *(const int4*)(col + g);
                    wreg[u] = *(const float4*)(wgt + g);
                }
            }
        }

        const int base = c * CHUNK;
        const int cntg = min(CHUNK, NN - base) >> 2;   // groups this chunk (32 or 8)

        // ---- prologue: groups 0,1 cand/weight + matched words ----
        int   cA = cbuf[b][t],      cB = cbuf[b][64 + t], cC = 0;
        float wA = wbuf[b][t],      wB = wbuf[b][64 + t], wC = 0.0f;
        unsigned mA = matched[((unsigned)cA) >> 5];
        unsigned sA = matched[((unsigned)base) >> 5];
        unsigned mB = matched[((unsigned)cB) >> 5];
        unsigned sB = matched[((unsigned)(base + 4)) >> 5];
        unsigned mC = 0u, sC = 0u;

        for (int G = 0; G < cntg; ++G) {
            const int i = base + G * 4;
            if (G + 2 < cntg) {               // cand/weight for group G+2
                cC = cbuf[b][(G + 2) * 64 + t];
                wC = wbuf[b][(G + 2) * 64 + t];
            }
            // ---- parallel validity for all 4 rows ----
            const int nb    = cA;
            const int nodeq = i + row;
            bool ok = (nb > nodeq)
                      && (((mA >> (nb & 31)) & 1u) == 0u)
                      && nb != jp0 && nb != jp1 && nb != jp2 && nb != jp3;
            float wm = ok ? wA : -INFINITY;
            unsigned ps = sA;                 // patched self word
            if (jp0 >= i && jp0 <= i + 3) ps |= 1u << (jp0 & 31);
            if (jp1 >= i && jp1 <= i + 3) ps |= 1u << (jp1 & 31);
            if (jp2 >= i && jp2 <= i + 3) ps |= 1u << (jp2 & 31);
            if (jp3 >= i && jp3 <= i + 3) ps |= 1u << (jp3 & 31);

            int  j0, j1v, j2v, j3v;
            bool h0, h1, h2, h3;
#define STEP(Q, JVAR, HVAR, LAST)                                              \
            {                                                                  \
                float m = row16_max(wm);                                       \
                unsigned long long bal = __ballot(wm == m);                    \
                float maxw = __int_as_float(                                   \
                    __builtin_amdgcn_readlane(__float_as_int(m), 16 * Q));     \
                bool selfq = ((ps >> ((i + Q) & 31)) & 1u) != 0u;              \
                bool has   = maxw > -INFINITY;                                 \
                unsigned b16 = (unsigned)((bal >> (16 * Q)) & 0xFFFFull);      \
                int lanewin = 16 * Q + (int)__builtin_ctz(b16 | 0x10000u);     \
                int jv = __builtin_amdgcn_readlane(cA, lanewin);               \
                JVAR = (!selfq && has) ? jv : -1;                              \
                HVAR = !selfq;                                                 \
                if (!LAST) {                                                   \
                    wm = (cA == JVAR) ? -INFINITY : wm;                        \
                    if (JVAR >= i && JVAR <= i + 3) ps |= 1u << (JVAR & 31);   \
                }                                                              \
            }
            STEP(0, j0,  h0, false)
            STEP(1, j1v, h1, false)
            STEP(2, j2v, h2, false)
            STEP(3, j3v, h3, true)
#undef STEP
            // ---- commit: lanes 0..3 write node i+t ----
            {
                bool hq = (t == 1) ? h1 : (t == 2) ? h2 : (t == 3) ? h3 : h0;
                int  jq = (t == 1) ? j1v : (t == 2) ? j2v : (t == 3) ? j3v : j0;
                if (t < 4) {
                    if (hq) {
                        cluster[i + t] = i + t;
                        partner[i + t] = jq;
                    }
                    if (jq >= 0) {            // jq >= 0 implies hq
                        cluster[jq] = i + t;
                        atomicOr(&matched[((unsigned)jq) >> 5], 1u << (jq & 31));
                    }
                }
            }
            // ---- matched-word prefetch for group G+2 (sees all grabs <= G) ----
            if (G + 2 < cntg) {
                mC = matched[((unsigned)cC) >> 5];
                sC = matched[((unsigned)(i + 8)) >> 5];
            }
            // ---- rotate ----
            cA = cB; wA = wB; cB = cC; wB = wC;
            mA = mB; mB = mC; sA = sB; sB = sC;
            jp0 = j0; jp1 = j1v; jp2 = j2v; jp3 = j3v;
        }
        __syncthreads();
    }
}

// x_out[c][f] = head ? max(x[c][f], x[partner][f]) : 0
__global__ void k_pool_x(const float* __restrict__ x, const int* __restrict__ cluster,
                         const int* __restrict__ partner, float* __restrict__ x_out) {
    int idx = blockIdx.x * blockDim.x + threadIdx.x;
    if (idx >= NN * FF) return;
    int c = idx >> 7;
    float v = 0.0f;
    if (cluster[c] == c) {
        v = x[idx];
        int p = partner[c];
        if (p >= 0) v = fmaxf(v, x[p * FF + (idx & (FF - 1))]);
    }
    x_out[idx] = v;
}

__global__ void k_pool_pos(const float* __restrict__ pos, const int* __restrict__ cluster,
                           const int* __restrict__ partner, float* __restrict__ pos_out) {
    int c = blockIdx.x * blockDim.x + threadIdx.x;
    if (c >= NN) return;
    float px = 0.0f, py = 0.0f;
    if (cluster[c] == c) {
        px = pos[2*c]; py = pos[2*c+1];
        int p = partner[c];
        if (p >= 0) {  // (a+b)*0.5 == (a+b)/2 exactly
            px = __fmul_rn(__fadd_rn(px, pos[2*p]),   0.5f);
            py = __fmul_rn(__fadd_rn(py, pos[2*p+1]), 0.5f);
        }
    }
    pos_out[2*c] = px; pos_out[2*c+1] = py;
}

// pooled edge indices (as float) + global max |cart| over non-self edges
__global__ void k_edges_max(const int* __restrict__ col, const int* __restrict__ cluster,
                            const float* __restrict__ pos_out, float* __restrict__ out_ei,
                            unsigned int* __restrict__ maxv) {
    float m = 0.0f;
    for (int e = blockIdx.x * blockDim.x + threadIdx.x; e < EE;
         e += gridDim.x * blockDim.x) {
        int rc = cluster[e >> 4];
        int cc = cluster[col[e]];
        out_ei[e]      = (float)rc;
        out_ei[EN + e] = (float)cc;
        if (rc != cc) {
            float dx = __fsub_rn(pos_out[2*cc],   pos_out[2*rc]);
            float dy = __fsub_rn(pos_out[2*cc+1], pos_out[2*rc+1]);
            m = fmaxf(m, fmaxf(fabsf(dx), fabsf(dy)));
        }
    }
    for (int off = 32; off > 0; off >>= 1) m = fmaxf(m, __shfl_down(m, off));
    if ((threadIdx.x & 63) == 0) atomicMax(maxv, __float_as_uint(m));
}

__global__ void k_attr(const int* __restrict__ col, const int* __restrict__ cluster,
                       const float* __restrict__ pos_out,
                       const unsigned int* __restrict__ maxv,
                       float* __restrict__ out_ei, float* __restrict__ out_attr) {
    int e = blockIdx.x * blockDim.x + threadIdx.x;
    if (e >= EN) return;
    if (e < EE) {
        int rc = cluster[e >> 4];
        int cc = cluster[col[e]];
        float a0 = 1.0f, a1 = 1.0f;
        if (rc != cc) {
            float denom = __fmul_rn(2.0f, __uint_as_float(*maxv));
            float dx = __fsub_rn(pos_out[2*cc],   pos_out[2*rc]);
            float dy = __fsub_rn(pos_out[2*cc+1], pos_out[2*rc+1]);
            a0 = __fadd_rn(__fdiv_rn(dx, denom), 0.5f);
            a1 = __fadd_rn(__fdiv_rn(dy, denom), 0.5f);
        }
        out_attr[2*e] = a0; out_attr[2*e+1] = a1;
    } else {
        int i = e - EE;  // self loops appended after the EE pooled edges
        out_ei[e]      = (float)i;
        out_ei[EN + e] = (float)i;
        out_attr[2*e] = 1.0f; out_attr[2*e+1] = 1.0f;
    }
}

extern "C" void kernel_launch(void* const* d_in, const int* in_sizes, int n_in,
                              void* d_out, int out_size, void* d_ws, size_t ws_size,
                              hipStream_t stream) {
    const float* x   = (const float*)d_in[0];
    const float* pos = (const float*)d_in[1];
    const int*   ei  = (const int*)d_in[2];
    const int*   col = ei + EE;   // row = e>>4 by construction

    char* ws = (char*)d_ws;
    int*          cnt     = (int*)(ws + WS_CNT);
    float*        dinv    = (float*)(ws + WS_DINV);
    float*        wgt     = (float*)(ws + WS_WGT);
    int*          cluster = (int*)(ws + WS_CLUSTER);
    int*          partner = (int*)(ws + WS_PARTNER);
    unsigned int* maxv    = (unsigned int*)(ws + WS_MAXV);

    float* out   = (float*)d_out;
    float* out_x    = out + OUT_X;
    float* out_pos  = out + OUT_POS;
    float* out_ei   = out + OUT_EI;
    float* out_attr = out + OUT_ATTR;

    k_zero<<<(NN + 255) / 256, 256, 0, stream>>>(cnt, maxv);
    k_deg<<<(EE + 255) / 256, 256, 0, stream>>>(col, cnt);
    k_dinv<<<(NN + 255) / 256, 256, 0, stream>>>(cnt, dinv);
    k_weight<<<(EE + 255) / 256, 256, 0, stream>>>(col, pos, dinv, wgt);
    k_match<<<1, 64, 0, stream>>>(col, wgt, cluster, partner);
    k_pool_x<<<(NN * FF + 255) / 256, 256, 0, stream>>>(x, cluster, partner, out_x);
    k_pool_pos<<<(NN + 255) / 256, 256, 0, stream>>>(pos, cluster, partner, out_pos);
    k_edges_max<<<1024, 256, 0, stream>>>(col, cluster, out_pos, out_ei, maxv);
    k_attr<<<(EN + 255) / 256, 256, 0, stream>>>(col, cluster, out_pos, maxv,
                                                 out_ei, out_attr);
}

// Round 9
// 15441.734 us; speedup vs baseline: 1.9807x; 1.3039x over previous
//
#include <hip/hip_runtime.h>
#include <math.h>

static constexpr int NN = 100000;          // nodes
static constexpr int DD = 16;              // out-degree
static constexpr int FF = 128;             // features
static constexpr int EE = NN * DD;         // 1,600,000 edges
static constexpr int EN = EE + NN;         // edges + self loops
static constexpr int MWORDS = (NN + 31) / 32;   // 3125
static constexpr int CHUNK  = 128;              // nodes per staged chunk
static constexpr int NCHUNK = (NN + CHUNK - 1) / CHUNK;  // 782 (last = 32 nodes)

// ---- d_ws layout (bytes) ----
static constexpr size_t WS_CNT     = 0;
static constexpr size_t WS_DINV    = 400000;
static constexpr size_t WS_WGT     = 800000;   // k_weight out; k_sort rewrites in-place as slist (int)
static constexpr size_t WS_CLUSTER = 7200000;
static constexpr size_t WS_PARTNER = 7600000;
static constexpr size_t WS_MAXV    = 8000000;

// ---- d_out layout (float32 elements) ----
static constexpr size_t OUT_X    = 0;                      // NN*FF
static constexpr size_t OUT_POS  = (size_t)NN * FF;        // NN*2
static constexpr size_t OUT_EI   = OUT_POS + (size_t)NN*2; // 2*EN
static constexpr size_t OUT_ATTR = OUT_EI + (size_t)2*EN;  // EN*2

__global__ void k_zero(int* __restrict__ cnt, unsigned int* __restrict__ maxv) {
    int i = blockIdx.x * blockDim.x + threadIdx.x;
    if (i < NN) cnt[i] = 0;
    if (i == 0) *maxv = 0u;
}

__global__ void k_deg(const int* __restrict__ col, int* __restrict__ cnt) {
    int e = blockIdx.x * blockDim.x + threadIdx.x;
    if (e < EE) atomicAdd(&cnt[col[e]], 1);
}

__global__ void k_dinv(const int* __restrict__ cnt, float* __restrict__ dinv) {
    int i = blockIdx.x * blockDim.x + threadIdx.x;
    if (i < NN) dinv[i] = __fdiv_rn(1.0f, __fadd_rn((float)cnt[i], 1e-8f));
}

// weight[e] = dist(pos[row],pos[col]) * (dinv[row]+dinv[col]); rn ops only (no FMA).
__global__ void k_weight(const int* __restrict__ col, const float* __restrict__ pos,
                         const float* __restrict__ dinv, float* __restrict__ wgt) {
    int e = blockIdx.x * blockDim.x + threadIdx.x;
    if (e >= EE) return;
    int r = e >> 4;
    int c = col[e];
    float dx = __fsub_rn(pos[2*r],   pos[2*c]);
    float dy = __fsub_rn(pos[2*r+1], pos[2*c+1]);
    float dist = __fsqrt_rn(__fadd_rn(__fmul_rn(dx, dx), __fmul_rn(dy, dy)));
    wgt[e] = __fmul_rn(dist, __fadd_rn(dinv[r], dinv[c]));
}

// Per-node candidate ranking (state-independent): sort 16 candidates by
// (weight desc, position asc) == jnp.argmax first-max order; statically drop
// nb <= i (never valid: visited nodes always have cluster >= 0). Writes the
// sorted candidate ids IN-PLACE over wgt (each thread reads its 16 weights
// before storing; the walk kernel reads only slist). Bitonic network: all
// indices compile-time -> registers (no scratch).
__global__ void k_sort(const int* __restrict__ col, float* wgt_io) {
    int i = blockIdx.x * blockDim.x + threadIdx.x;
    if (i >= NN) return;
    const int4*   cp = (const int4*)(col + 16 * (size_t)i);
    const float4* wp = (const float4*)(wgt_io + 16 * (size_t)i);
    int4   c0 = cp[0], c1 = cp[1], c2 = cp[2], c3 = cp[3];
    float4 w0 = wp[0], w1 = wp[1], w2 = wp[2], w3 = wp[3];
    const int   nbv[16] = {c0.x,c0.y,c0.z,c0.w, c1.x,c1.y,c1.z,c1.w,
                           c2.x,c2.y,c2.z,c2.w, c3.x,c3.y,c3.z,c3.w};
    const float wv[16]  = {w0.x,w0.y,w0.z,w0.w, w1.x,w1.y,w1.z,w1.w,
                           w2.x,w2.y,w2.z,w2.w, w3.x,w3.y,w3.z,w3.w};
    unsigned long long key[16];
    int nb[16];
#pragma unroll
    for (int k = 0; k < 16; ++k) {
        bool val = nbv[k] > i;   // weights >= 0 -> uint bits are order-monotone
        key[k] = val ? ((1ull << 40)
                        | ((unsigned long long)__float_as_uint(wv[k]) << 5)
                        | (unsigned long long)(15 - k))
                     : 0ull;
        nb[k] = val ? nbv[k] : -1;
    }
    // bitonic sort, descending by key (invalid key=0 sinks to the tail)
#pragma unroll
    for (int kk = 2; kk <= 16; kk <<= 1) {
#pragma unroll
        for (int jj = kk >> 1; jj > 0; jj >>= 1) {
#pragma unroll
            for (int ii = 0; ii < 16; ++ii) {
                int ll = ii ^ jj;
                if (ll > ii) {
                    bool desc = (ii & kk) == 0;
                    bool sw = desc ? (key[ii] < key[ll]) : (key[ii] > key[ll]);
                    if (sw) {
                        unsigned long long tk = key[ii]; key[ii] = key[ll]; key[ll] = tk;
                        int tn = nb[ii]; nb[ii] = nb[ll]; nb[ll] = tn;
                    }
                }
            }
        }
    }
    int* sp = (int*)wgt_io + 16 * (size_t)i;
    *(int4*)(sp + 0)  = make_int4(nb[0],  nb[1],  nb[2],  nb[3]);
    *(int4*)(sp + 4)  = make_int4(nb[4],  nb[5],  nb[6],  nb[7]);
    *(int4*)(sp + 8)  = make_int4(nb[8],  nb[9],  nb[10], nb[11]);
    *(int4*)(sp + 12) = make_int4(nb[12], nb[13], nb[14], nb[15]);
}

static __device__ __forceinline__ unsigned mword(int c) {
    unsigned w = ((unsigned)c) >> 5;       // c = -1 -> huge -> clamp
    return w < (unsigned)MWORDS ? w : 0u;
}

// Exact graclus matching, 4 nodes per wave-iteration (4 rows x 16 sorted
// candidates). No float ops on the critical path: validity bit + one ballot,
// then per row ctz/readlane + SALU mask patches. Grabs in LDS bitset;
// prefetch at group depth 2 patched by previous group's grabs (jp0..3).
__global__ void __launch_bounds__(64)
k_match(const int* __restrict__ slist, int* __restrict__ cluster,
        int* __restrict__ partner) {
    __shared__ unsigned int matched[MWORDS];
    __shared__ int cbuf[2][CHUNK * 16 + 64];

    const int t = threadIdx.x;
    for (int idx = t; idx < MWORDS; idx += 64) matched[idx] = 0u;

    int4 creg[8] = {};

    // stage chunk 0: global -> regs -> LDS buf0
#pragma unroll 8
    for (int u = 0; u < 8; ++u) {
        int g = u * 256 + t * 4;
        if (g < EE) creg[u] = *(const int4*)(slist + g);
    }
#pragma unroll 8
    for (int u = 0; u < 8; ++u) {
        int off = u * 256 + t * 4;
        *(int4*)&cbuf[0][off] = creg[u];
    }
    // issue loads for chunk 1
#pragma unroll 8
    for (int u = 0; u < 8; ++u) {
        int g = 2048 + u * 256 + t * 4;
        if (g < EE) creg[u] = *(const int4*)(slist + g);
    }
    __syncthreads();

    int jp0 = -1, jp1 = -1, jp2 = -1, jp3 = -1;  // previous group's grabs

    for (int c = 0; c < NCHUNK; ++c) {
        const int b = c & 1;
        if (c + 1 < NCHUNK) {   // write chunk c+1 into the other buffer
            const int ob = (c + 1) & 1;
#pragma unroll 8
            for (int u = 0; u < 8; ++u) {
                int off = u * 256 + t * 4;
                *(int4*)&cbuf[ob][off] = creg[u];
            }
        }
        if (c + 2 < NCHUNK) {   // issue global loads for chunk c+2
            const int gb = (c + 2) * 2048;
#pragma unroll 8
            for (int u = 0; u < 8; ++u) {
                int g = gb + u * 256 + t * 4;
                if (g < EE) creg[u] = *(const int4*)(slist + g);
            }
        }

        const int base = c * CHUNK;
        const int cntg = min(CHUNK, NN - base) >> 2;   // groups (32 or 8)

        int cA = cbuf[b][t], cB = cbuf[b][64 + t], cC = 0;
        unsigned mA = matched[mword(cA)];
        unsigned sA = matched[((unsigned)base) >> 5];
        unsigned mB = matched[mword(cB)];
        unsigned sB = matched[((unsigned)(base + 4)) >> 5];
        unsigned mC = 0u, sC = 0u;

        for (int G = 0; G < cntg; ++G) {
            const int i = base + G * 4;
            if (G + 2 < cntg) cC = cbuf[b][(G + 2) * 64 + t];

            // ---- validity for all 4 rows, one ballot ----
            const int nb = cA;   // sorted candidate (or -1); nb > owner-node statically
            bool ok = (nb >= 0)
                      && (((mA >> (nb & 31)) & 1u) == 0u)
                      && nb != jp0 && nb != jp1 && nb != jp2 && nb != jp3;
            unsigned long long bal = __ballot(ok);
            unsigned ps = sA;                 // patched self word (i..i+3 same word)
            if (jp0 >= i && jp0 <= i + 3) ps |= 1u << (jp0 & 31);
            if (jp1 >= i && jp1 <= i + 3) ps |= 1u << (jp1 & 31);
            if (jp2 >= i && jp2 <= i + 3) ps |= 1u << (jp2 & 31);
            if (jp3 >= i && jp3 <= i + 3) ps |= 1u << (jp3 & 31);

            int  j0, j1v, j2v, j3v;
            bool h0, h1, h2, h3;
#define ROW(Q, JVAR, HVAR, LAST)                                               \
            {                                                                  \
                unsigned slice = (unsigned)((bal >> (16 * Q)) & 0xFFFFull);    \
                bool selfq = ((ps >> ((i + Q) & 31)) & 1u) != 0u;              \
                HVAR = !selfq;                                                 \
                int jv = -1;                                                   \
                if (!selfq && slice) {                                         \
                    int lanewin = 16 * Q + (int)__builtin_ctz(slice);          \
                    jv = __builtin_amdgcn_readlane(cA, lanewin);               \
                }                                                              \
                JVAR = jv;                                                     \
                if (!LAST && jv >= 0) {                                        \
                    bal &= ~__ballot(cA == jv);                                \
                    if (jv <= i + 3) ps |= 1u << (jv & 31);  /* jv > i always */ \
                }                                                              \
            }
            ROW(0, j0,  h0, false)
            ROW(1, j1v, h1, false)
            ROW(2, j2v, h2, false)
            ROW(3, j3v, h3, true)
#undef ROW
            // ---- commit: lanes 0..3 write node i+t ----
            {
                bool hq = (t == 1) ? h1 : (t == 2) ? h2 : (t == 3) ? h3 : h0;
                int  jq = (t == 1) ? j1v : (t == 2) ? j2v : (t == 3) ? j3v : j0;
                if (t < 4) {
                    if (hq) {
                        cluster[i + t] = i + t;
                        partner[i + t] = jq;
                    }
                    if (jq >= 0) {            // jq >= 0 implies hq
                        cluster[jq] = i + t;
                        atomicOr(&matched[((unsigned)jq) >> 5], 1u << (jq & 31));
                    }
                }
            }
            // ---- prefetch for group G+2 (sees all grabs <= G) ----
            if (G + 2 < cntg) {
                mC = matched[mword(cC)];
                sC = matched[((unsigned)(i + 8)) >> 5];
            }
            // ---- rotate ----
            cA = cB; cB = cC;
            mA = mB; mB = mC; sA = sB; sB = sC;
            jp0 = j0; jp1 = j1v; jp2 = j2v; jp3 = j3v;
        }
        __syncthreads();
    }
}

// x_out[c][f] = head ? max(x[c][f], x[partner][f]) : 0
__global__ void k_pool_x(const float* __restrict__ x, const int* __restrict__ cluster,
                         const int* __restrict__ partner, float* __restrict__ x_out) {
    int idx = blockIdx.x * blockDim.x + threadIdx.x;
    if (idx >= NN * FF) return;
    int c = idx >> 7;
    float v = 0.0f;
    if (cluster[c] == c) {
        v = x[idx];
        int p = partner[c];
        if (p >= 0) v = fmaxf(v, x[p * FF + (idx & (FF - 1))]);
    }
    x_out[idx] = v;
}

__global__ void k_pool_pos(const float* __restrict__ pos, const int* __restrict__ cluster,
                           const int* __restrict__ partner, float* __restrict__ pos_out) {
    int c = blockIdx.x * blockDim.x + threadIdx.x;
    if (c >= NN) return;
    float px = 0.0f, py = 0.0f;
    if (cluster[c] == c) {
        px = pos[2*c]; py = pos[2*c+1];
        int p = partner[c];
        if (p >= 0) {  // (a+b)*0.5 == (a+b)/2 exactly
            px = __fmul_rn(__fadd_rn(px, pos[2*p]),   0.5f);
            py = __fmul_rn(__fadd_rn(py, pos[2*p+1]), 0.5f);
        }
    }
    pos_out[2*c] = px; pos_out[2*c+1] = py;
}

// pooled edge indices (as float) + global max |cart| over non-self edges
__global__ void k_edges_max(const int* __restrict__ col, const int* __restrict__ cluster,
                            const float* __restrict__ pos_out, float* __restrict__ out_ei,
                            unsigned int* __restrict__ maxv) {
    float m = 0.0f;
    for (int e = blockIdx.x * blockDim.x + threadIdx.x; e < EE;
         e += gridDim.x * blockDim.x) {
        int rc = cluster[e >> 4];
        int cc = cluster[col[e]];
        out_ei[e]      = (float)rc;
        out_ei[EN + e] = (float)cc;
        if (rc != cc) {
            float dx = __fsub_rn(pos_out[2*cc],   pos_out[2*rc]);
            float dy = __fsub_rn(pos_out[2*cc+1], pos_out[2*rc+1]);
            m = fmaxf(m, fmaxf(fabsf(dx), fabsf(dy)));
        }
    }
    for (int off = 32; off > 0; off >>= 1) m = fmaxf(m, __shfl_down(m, off));
    if ((threadIdx.x & 63) == 0) atomicMax(maxv, __float_as_uint(m));
}

__global__ void k_attr(const int* __restrict__ col, const int* __restrict__ cluster,
                       const float* __restrict__ pos_out,
                       const unsigned int* __restrict__ maxv,
                       float* __restrict__ out_ei, float* __restrict__ out_attr) {
    int e = blockIdx.x * blockDim.x + threadIdx.x;
    if (e >= EN) return;
    if (e < EE) {
        int rc = cluster[e >> 4];
        int cc = cluster[col[e]];
        float a0 = 1.0f, a1 = 1.0f;
        if (rc != cc) {
            float denom = __fmul_rn(2.0f, __uint_as_float(*maxv));
            float dx = __fsub_rn(pos_out[2*cc],   pos_out[2*rc]);
            float dy = __fsub_rn(pos_out[2*cc+1], pos_out[2*rc+1]);
            a0 = __fadd_rn(__fdiv_rn(dx, denom), 0.5f);
            a1 = __fadd_rn(__fdiv_rn(dy, denom), 0.5f);
        }
        out_attr[2*e] = a0; out_attr[2*e+1] = a1;
    } else {
        int i = e - EE;  // self loops appended after the EE pooled edges
        out_ei[e]      = (float)i;
        out_ei[EN + e] = (float)i;
        out_attr[2*e] = 1.0f; out_attr[2*e+1] = 1.0f;
    }
}

extern "C" void kernel_launch(void* const* d_in, const int* in_sizes, int n_in,
                              void* d_out, int out_size, void* d_ws, size_t ws_size,
                              hipStream_t stream) {
    const float* x   = (const float*)d_in[0];
    const float* pos = (const float*)d_in[1];
    const int*   ei  = (const int*)d_in[2];
    const int*   col = ei + EE;   // row = e>>4 by construction

    char* ws = (char*)d_ws;
    int*          cnt     = (int*)(ws + WS_CNT);
    float*        dinv    = (float*)(ws + WS_DINV);
    float*        wgt     = (float*)(ws + WS_WGT);
    int*          slist   = (int*)(ws + WS_WGT);    // k_sort rewrites wgt in-place
    int*          cluster = (int*)(ws + WS_CLUSTER);
    int*          partner = (int*)(ws + WS_PARTNER);
    unsigned int* maxv    = (unsigned int*)(ws + WS_MAXV);

    float* out   = (float*)d_out;
    float* out_x    = out + OUT_X;
    float* out_pos  = out + OUT_POS;
    float* out_ei   = out + OUT_EI;
    float* out_attr = out + OUT_ATTR;

    k_zero<<<(NN + 255) / 256, 256, 0, stream>>>(cnt, maxv);
    k_deg<<<(EE + 255) / 256, 256, 0, stream>>>(col, cnt);
    k_dinv<<<(NN + 255) / 256, 256, 0, stream>>>(cnt, dinv);
    k_weight<<<(EE + 255) / 256, 256, 0, stream>>>(col, pos, dinv, wgt);
    k_sort<<<(NN + 255) / 256, 256, 0, stream>>>(col, wgt);
    k_match<<<1, 64, 0, stream>>>(slist, cluster, partner);
    k_pool_x<<<(NN * FF + 255) / 256, 256, 0, stream>>>(x, cluster, partner, out_x);
    k_pool_pos<<<(NN + 255) / 256, 256, 0, stream>>>(pos, cluster, partner, out_pos);
    k_edges_max<<<1024, 256, 0, stream>>>(col, cluster, out_pos, out_ei, maxv);
    k_attr<<<(EN + 255) / 256, 256, 0, stream>>>(col, cluster, out_pos, maxv,
                                                 out_ei, out_attr);
}